// Round 10
// baseline (857.555 us; speedup 1.0000x reference)
//
#include <hip/hip_runtime.h>
#include <cstdint>

#define K_NE 16
// DIAGNOSTIC ROUND: score body repeated x4, topk read+extract repeated x6
// (idempotent recompute -> identical outputs) so both kernels exceed the
// harness's ~235us poison-fill dispatches and surface in rocprof top-5.
#define SCORE_REP 4
#define TOPK_REP 6
constexpr int B = 8, N = 2048, F = 128;
constexpr size_t NSEND = (size_t)B * N;                 // 16384 sender rows
constexpr size_t EDGE_FLOATS = NSEND * K_NE * 256;      // 67,108,864
constexpr size_t SEND_FLOATS = (size_t)B * N * N;       // 33,554,432

// ---------------- K0: row norms (one wave per 128-float row) ----------------
__global__ __launch_bounds__(256) void norms_kernel(const float* __restrict__ X,
                                                    float* __restrict__ out) {
    int tid = blockIdx.x * 256 + threadIdx.x;
    int w = tid >> 6, lane = tid & 63;
    const float2 v = ((const float2*)(X + (size_t)w * F))[lane];
    float s = v.x * v.x + v.y * v.y;
    #pragma unroll
    for (int off = 32; off; off >>= 1) s += __shfl_xor(s, off);
    if (lane == 0) out[w] = s;
}

// ---------------- K1: score matrix (r6 structure, x4 repeat) ----------------
// 128x128 tile, 256 threads, 8x8 micro-tile, BK=8 k-major LDS dbuf.
// Per-(r,c): single fmaf chain, k ascending -> bit-identical selection.
__global__ __launch_bounds__(256) void score_kernel(const float* __restrict__ S,
                                                    const float* __restrict__ Rv,
                                                    const float* __restrict__ x2,
                                                    const float* __restrict__ y2,
                                                    float* __restrict__ scores) {
    __shared__ float As[2][8][128];   // [buf][k][row]
    __shared__ float Bs[2][8][128];   // [buf][k][col]
    const int bx = blockIdx.x, by = blockIdx.y, bz = blockIdx.z;
    const int t = threadIdx.x;
    const int tx = t & 15, ty = t >> 4;
    const float* Sb = S  + (size_t)bz * N * F + (size_t)by * 128 * F;
    const float* Rb = Rv + (size_t)bz * N * F + (size_t)bx * 128 * F;

    const int srow = t >> 1;            // 0..127
    const int skq  = (t & 1) << 2;      // 0 or 4
    const float* pa = Sb + (size_t)srow * F + skq;
    const float* pb = Rb + (size_t)srow * F + skq;

    float* outb = scores + (size_t)bz * N * N;
    const float* x2b = x2 + (size_t)bz * N;
    const float* y2b = y2 + (size_t)bz * N;

    #pragma unroll 1
    for (int rep = 0; rep < SCORE_REP; ++rep) {
        float4 a = *(const float4*)(pa);
        float4 b = *(const float4*)(pb);
        As[0][skq + 0][srow] = a.x; As[0][skq + 1][srow] = a.y;
        As[0][skq + 2][srow] = a.z; As[0][skq + 3][srow] = a.w;
        Bs[0][skq + 0][srow] = b.x; Bs[0][skq + 1][srow] = b.y;
        Bs[0][skq + 2][srow] = b.z; Bs[0][skq + 3][srow] = b.w;
        __syncthreads();

        float acc[8][8] = {};

        for (int kc = 0; kc < 16; ++kc) {   // 16 chunks of BK=8
            const int cur = kc & 1;
            if (kc < 15) {                  // issue next chunk's loads early
                a = *(const float4*)(pa + ((kc + 1) << 3));
                b = *(const float4*)(pb + ((kc + 1) << 3));
            }
            #pragma unroll
            for (int k = 0; k < 8; ++k) {
                const float4 af0 = *(const float4*)(&As[cur][k][ty * 4]);
                const float4 af1 = *(const float4*)(&As[cur][k][64 + ty * 4]);
                const float4 bf0 = *(const float4*)(&Bs[cur][k][tx * 4]);
                const float4 bf1 = *(const float4*)(&Bs[cur][k][64 + tx * 4]);
                const float av[8] = {af0.x, af0.y, af0.z, af0.w, af1.x, af1.y, af1.z, af1.w};
                const float bv[8] = {bf0.x, bf0.y, bf0.z, bf0.w, bf1.x, bf1.y, bf1.z, bf1.w};
                #pragma unroll
                for (int i = 0; i < 8; ++i)
                    #pragma unroll
                    for (int j = 0; j < 8; ++j)
                        acc[i][j] = fmaf(av[i], bv[j], acc[i][j]);
            }
            if (kc < 15) {
                const int nxt = cur ^ 1;    // write next buffer; one barrier/chunk
                As[nxt][skq + 0][srow] = a.x; As[nxt][skq + 1][srow] = a.y;
                As[nxt][skq + 2][srow] = a.z; As[nxt][skq + 3][srow] = a.w;
                Bs[nxt][skq + 0][srow] = b.x; Bs[nxt][skq + 1][srow] = b.y;
                Bs[nxt][skq + 2][srow] = b.z; Bs[nxt][skq + 3][srow] = b.w;
                __syncthreads();
            }
        }

        float yv[8];
        #pragma unroll
        for (int c = 0; c < 4; ++c) {
            yv[c]     = y2b[bx * 128 + tx * 4 + c];
            yv[4 + c] = y2b[bx * 128 + 64 + tx * 4 + c];
        }
        #pragma unroll
        for (int i = 0; i < 8; ++i) {
            const int r = by * 128 + ty * 4 + (i & 3) + 64 * (i >> 2);
            const float xv = x2b[r];
            float* orow = outb + (size_t)r * N + bx * 128;
            float4 o0, o1;
            o0.x = fabsf((-2.0f * acc[i][0] + xv) + yv[0]);
            o0.y = fabsf((-2.0f * acc[i][1] + xv) + yv[1]);
            o0.z = fabsf((-2.0f * acc[i][2] + xv) + yv[2]);
            o0.w = fabsf((-2.0f * acc[i][3] + xv) + yv[3]);
            o1.x = fabsf((-2.0f * acc[i][4] + xv) + yv[4]);
            o1.y = fabsf((-2.0f * acc[i][5] + xv) + yv[5]);
            o1.z = fabsf((-2.0f * acc[i][6] + xv) + yv[6]);
            o1.w = fabsf((-2.0f * acc[i][7] + xv) + yv[7]);
            *(float4*)(orow + tx * 4)      = o0;
            *(float4*)(orow + 64 + tx * 4) = o1;
        }
        __syncthreads();   // all reads of this rep's bufs done before next rep restages
    }
}

// ------- K2: fused top-16 + conn row + edge rows (r6 structure, x6 scan) ----
__global__ __launch_bounds__(256) void topk_fused_kernel(const float* __restrict__ S,
                                                         const float* __restrict__ Rv,
                                                         float* __restrict__ scores,
                                                         float* __restrict__ edges_out) {
    __shared__ uint32_t rowbuf[4][N];     // 32 KB, lane-private slices
    const int t = threadIdx.x;
    const int lane = t & 63;
    const int w = t >> 6;
    const int g = blockIdx.x * 4 + w;     // global sender id 0..16383
    const int bz = g >> 11;               // batch
    uint32_t* lds = rowbuf[w];
    float* srowp = scores + (size_t)g * N;
    const uint4* sr = (const uint4*)srowp;

    int ixs[16];
    #pragma unroll 1
    for (int rep = 0; rep < TOPK_REP; ++rep) {
        // ---- load row -> LDS keys; per-lane (key, idx) min ----------------
        uint32_t mk = 0xFFFFFFFFu, mi = 0;
        #pragma unroll
        for (int jj = 0; jj < 8; ++jj) {
            uint4 u = sr[jj * 64 + lane];
            *(uint4*)(&lds[jj * 256 + lane * 4]) = u;
            const uint32_t base = (uint32_t)(jj * 256 + lane * 4);
            if (u.x < mk) { mk = u.x; mi = base; }
            if (u.y < mk) { mk = u.y; mi = base + 1; }
            if (u.z < mk) { mk = u.z; mi = base + 2; }
            if (u.w < mk) { mk = u.w; mi = base + 3; }
        }
        // ---- 16 extractions: butterfly min + owner delete/rescan ----------
        #pragma unroll
        for (int it = 0; it < 16; ++it) {
            const uint32_t ck = mk, ci = mi;
            uint32_t gk = mk, gi = mi;
            #pragma unroll
            for (int off = 32; off; off >>= 1) {
                uint32_t ok = (uint32_t)__shfl_xor((int)gk, off);
                uint32_t oi = (uint32_t)__shfl_xor((int)gi, off);
                if (ok < gk || (ok == gk && oi < gi)) { gk = ok; gi = oi; }
            }
            ixs[it] = (int)gi;
            if (ck == gk && ci == gi) {       // unique owner lane
                lds[gi] = 0xFFFFFFFFu;        // delete
                mk = 0xFFFFFFFFu; mi = 0;
                #pragma unroll
                for (int jj = 0; jj < 8; ++jj) {
                    uint4 u = *(const uint4*)(&lds[jj * 256 + lane * 4]);
                    const uint32_t base = (uint32_t)(jj * 256 + lane * 4);
                    if (u.x < mk) { mk = u.x; mi = base; }
                    if (u.y < mk) { mk = u.y; mi = base + 1; }
                    if (u.z < mk) { mk = u.z; mi = base + 2; }
                    if (u.w < mk) { mk = u.w; mi = base + 3; }
                }
            }
        }
        // keep each rep's extraction live (rule #17: DCE guard)
        asm volatile("" :: "v"(ixs[0]), "v"(ixs[15]));
    }

    // ---- ranks: output slot = ascending receiver-index position -----------
    int rank[16];
    #pragma unroll
    for (int e = 0; e < 16; ++e) {
        int r = 0;
        #pragma unroll
        for (int f = 0; f < 16; ++f) r += (ixs[f] < ixs[e]) ? 1 : 0;
        rank[e] = r;
    }

    // ---- connectivity row (overwrites this wave's score row) --------------
    uint32_t mask = 0;
    #pragma unroll
    for (int e = 0; e < 16; ++e) {
        const int ix = ixs[e];
        const int lane_t = (ix >> 2) & 63;
        const int bitpos = ((ix >> 8) << 2) | (ix & 3);
        if (lane == lane_t) mask |= (1u << bitpos);
    }
    #pragma unroll
    for (int j = 0; j < 8; ++j) {
        float4 v;
        v.x = (mask >> (j * 4 + 0)) & 1u ? 1.f : 0.f;
        v.y = (mask >> (j * 4 + 1)) & 1u ? 1.f : 0.f;
        v.z = (mask >> (j * 4 + 2)) & 1u ? 1.f : 0.f;
        v.w = (mask >> (j * 4 + 3)) & 1u ? 1.f : 0.f;
        *(float4*)(srowp + j * 256 + lane * 4) = v;
    }

    // ---- edge rows: [sender_feat(128) | recv_feat(128)] -------------------
    const float* srow = S + (size_t)g * F;
    const float* rb = Rv + (size_t)bz * N * F;
    float4 vs = {0.f, 0.f, 0.f, 0.f};
    if (lane < 32) vs = *(const float4*)(srow + lane * 4);
    #pragma unroll
    for (int e = 0; e < 16; ++e) {
        float4 v = vs;
        if (lane >= 32)
            v = *(const float4*)(rb + (size_t)ixs[e] * F + (lane - 32) * 4);
        *(float4*)(edges_out + ((size_t)g * K_NE + rank[e]) * 256 + lane * 4) = v;
    }
}

extern "C" void kernel_launch(void* const* d_in, const int* in_sizes, int n_in,
                              void* d_out, int out_size, void* d_ws, size_t ws_size,
                              hipStream_t stream) {
    (void)in_sizes; (void)n_in; (void)out_size; (void)ws_size;
    const float* recv = (const float*)d_in[0];
    const float* send = (const float*)d_in[1];
    float* out = (float*)d_out;
    float* sender_mat = out + EDGE_FLOATS;       // score scratch, then conn matrix
    float* x2 = (float*)((char*)d_ws + (262144u * 4));
    float* y2 = x2 + NSEND;

    norms_kernel<<<4096, 256, 0, stream>>>(send, x2);
    norms_kernel<<<4096, 256, 0, stream>>>(recv, y2);
    dim3 g1(16, 16, 8);
    score_kernel<<<g1, 256, 0, stream>>>(send, recv, x2, y2, sender_mat);
    topk_fused_kernel<<<4096, 256, 0, stream>>>(send, recv, sender_mat, out);
}

// Round 11
// 214.393 us; speedup vs baseline: 3.9999x; 3.9999x over previous
//
#include <hip/hip_runtime.h>
#include <cstdint>

#define K_NE 16
constexpr int B = 8, N = 2048, F = 128;
constexpr size_t NSEND = (size_t)B * N;                 // 16384 sender rows
constexpr size_t EDGE_FLOATS = NSEND * K_NE * 256;      // 67,108,864
constexpr size_t SEND_FLOATS = (size_t)B * N * N;       // 33,554,432

typedef _Float16 half8 __attribute__((ext_vector_type(8)));
typedef _Float16 half4 __attribute__((ext_vector_type(4)));
typedef float floatx4 __attribute__((ext_vector_type(4)));

// ---------------- K0: row norms (one wave per 128-float row) ----------------
__global__ __launch_bounds__(256) void norms_kernel(const float* __restrict__ X,
                                                    float* __restrict__ out) {
    int tid = blockIdx.x * 256 + threadIdx.x;
    int w = tid >> 6, lane = tid & 63;
    const float2 v = ((const float2*)(X + (size_t)w * F))[lane];
    float s = v.x * v.x + v.y * v.y;
    #pragma unroll
    for (int off = 32; off; off >>= 1) s += __shfl_xor(s, off);
    if (lane == 0) out[w] = s;
}

// ---------------- K0b: f32 -> (f16 hi, f16 lo) split ------------------------
// a = hi + lo with hi = f16(a), lo = f16(a - hi); dropped term in the dot is
// <= 2^-22 relative -- far below the f32 reassociation noise the selection
// already tolerates (absmax stayed 0 for 8 rounds of fmaf-chain variants).
__global__ __launch_bounds__(256) void convert_kernel(const float* __restrict__ S,
                                                      const float* __restrict__ Rv,
                                                      _Float16* __restrict__ SH,
                                                      _Float16* __restrict__ SL,
                                                      _Float16* __restrict__ RH,
                                                      _Float16* __restrict__ RL) {
    const int i = blockIdx.x * 256 + threadIdx.x;   // quad index
    const int half_n = (int)(NSEND * F / 4);        // 524288 quads per matrix
    const float* X; _Float16 *H, *L; int q;
    if (i < half_n) { X = S;  H = SH; L = SL; q = i; }
    else            { X = Rv; H = RH; L = RL; q = i - half_n; }
    const float4 v = ((const float4*)X)[q];
    half4 h, l;
    h.x = (_Float16)v.x; l.x = (_Float16)(v.x - (float)h.x);
    h.y = (_Float16)v.y; l.y = (_Float16)(v.y - (float)h.y);
    h.z = (_Float16)v.z; l.z = (_Float16)(v.z - (float)h.z);
    h.w = (_Float16)v.w; l.w = (_Float16)(v.w - (float)h.w);
    *(half4*)(H + 4 * (size_t)q) = h;
    *(half4*)(L + 4 * (size_t)q) = l;
}

// ---------------- K1: MFMA score matrix  dist = |x2+y2-2*dot| ---------------
// 128x128 block tile, 4 waves, each wave 64x64 = 4x4 fragments of 16x16.
// mfma_f32_16x16x32_f16, fp16 hi/lo split: acc += ah*bh + ah*bl + al*bh.
// Fragments loaded directly from global (L2-resident): lane layout for A is
// row=lane&15, k=8*(lane>>4)+j (8 contiguous halves = 16B); B symmetric from
// row-major receivers (B^T input). C/D: col=lane&15, row=(lane>>4)*4+reg
// [verified m89]. No LDS, no barriers.
__global__ __launch_bounds__(256) void score_mfma_kernel(
        const _Float16* __restrict__ SH, const _Float16* __restrict__ SL,
        const _Float16* __restrict__ RH, const _Float16* __restrict__ RL,
        const float* __restrict__ x2, const float* __restrict__ y2,
        float* __restrict__ scores) {
    const int bx = blockIdx.x, by = blockIdx.y, bz = blockIdx.z;
    const int t = threadIdx.x, lane = t & 63, wv = t >> 6;
    const int row0 = by * 128 + (wv >> 1) * 64;   // batch-local sender base
    const int col0 = bx * 128 + (wv & 1) * 64;    // batch-local receiver base
    const int lr = lane & 15, lk = (lane >> 4) * 8;

    const size_t sOff = ((size_t)(bz * N + row0 + lr)) * F + lk;
    const size_t rOff = ((size_t)(bz * N + col0 + lr)) * F + lk;
    const _Float16* pSH = SH + sOff;
    const _Float16* pSL = SL + sOff;
    const _Float16* pRH = RH + rOff;
    const _Float16* pRL = RL + rOff;

    floatx4 acc[4][4] = {};

    #pragma unroll 1
    for (int ks = 0; ks < 4; ++ks) {
        const int ko = ks * 32;
        half8 ah[4], al[4];
        #pragma unroll
        for (int i = 0; i < 4; ++i) {
            ah[i] = *(const half8*)(pSH + (size_t)i * 16 * F + ko);
            al[i] = *(const half8*)(pSL + (size_t)i * 16 * F + ko);
        }
        #pragma unroll
        for (int j = 0; j < 4; ++j) {
            const half8 bh = *(const half8*)(pRH + (size_t)j * 16 * F + ko);
            const half8 bl = *(const half8*)(pRL + (size_t)j * 16 * F + ko);
            #pragma unroll
            for (int i = 0; i < 4; ++i) {
                acc[i][j] = __builtin_amdgcn_mfma_f32_16x16x32_f16(ah[i], bh, acc[i][j], 0, 0, 0);
                acc[i][j] = __builtin_amdgcn_mfma_f32_16x16x32_f16(ah[i], bl, acc[i][j], 0, 0, 0);
                acc[i][j] = __builtin_amdgcn_mfma_f32_16x16x32_f16(al[i], bh, acc[i][j], 0, 0, 0);
            }
        }
    }

    float* outb = scores + (size_t)bz * N * N;
    const float* x2b = x2 + (size_t)bz * N;
    const float* y2b = y2 + (size_t)bz * N;
    #pragma unroll
    for (int j = 0; j < 4; ++j) {
        const int col = col0 + j * 16 + lr;
        const float yv = y2b[col];
        #pragma unroll
        for (int i = 0; i < 4; ++i) {
            #pragma unroll
            for (int r = 0; r < 4; ++r) {
                const int row = row0 + i * 16 + (lane >> 4) * 4 + r;
                const float d = acc[i][j][r];
                outb[(size_t)row * N + col] = fabsf((-2.0f * d + x2b[row]) + yv);
            }
        }
    }
}

// ------- K2: fused top-16 + connectivity row + edge rows (r6 version) -------
__global__ __launch_bounds__(256) void topk_fused_kernel(const float* __restrict__ S,
                                                         const float* __restrict__ Rv,
                                                         float* __restrict__ scores,
                                                         float* __restrict__ edges_out) {
    __shared__ uint32_t rowbuf[4][N];     // 32 KB, lane-private slices
    const int t = threadIdx.x;
    const int lane = t & 63;
    const int w = t >> 6;
    const int g = blockIdx.x * 4 + w;     // global sender id 0..16383
    const int bz = g >> 11;               // batch
    uint32_t* lds = rowbuf[w];
    float* srowp = scores + (size_t)g * N;
    const uint4* sr = (const uint4*)srowp;

    uint32_t mk = 0xFFFFFFFFu, mi = 0;
    #pragma unroll
    for (int jj = 0; jj < 8; ++jj) {
        uint4 u = sr[jj * 64 + lane];
        *(uint4*)(&lds[jj * 256 + lane * 4]) = u;
        const uint32_t base = (uint32_t)(jj * 256 + lane * 4);
        if (u.x < mk) { mk = u.x; mi = base; }
        if (u.y < mk) { mk = u.y; mi = base + 1; }
        if (u.z < mk) { mk = u.z; mi = base + 2; }
        if (u.w < mk) { mk = u.w; mi = base + 3; }
    }

    int ixs[16];
    #pragma unroll
    for (int it = 0; it < 16; ++it) {
        const uint32_t ck = mk, ci = mi;
        uint32_t gk = mk, gi = mi;
        #pragma unroll
        for (int off = 32; off; off >>= 1) {
            uint32_t ok = (uint32_t)__shfl_xor((int)gk, off);
            uint32_t oi = (uint32_t)__shfl_xor((int)gi, off);
            if (ok < gk || (ok == gk && oi < gi)) { gk = ok; gi = oi; }
        }
        ixs[it] = (int)gi;
        if (ck == gk && ci == gi) {       // unique owner lane
            lds[gi] = 0xFFFFFFFFu;        // delete
            mk = 0xFFFFFFFFu; mi = 0;     // rescan own 32 slots
            #pragma unroll
            for (int jj = 0; jj < 8; ++jj) {
                uint4 u = *(const uint4*)(&lds[jj * 256 + lane * 4]);
                const uint32_t base = (uint32_t)(jj * 256 + lane * 4);
                if (u.x < mk) { mk = u.x; mi = base; }
                if (u.y < mk) { mk = u.y; mi = base + 1; }
                if (u.z < mk) { mk = u.z; mi = base + 2; }
                if (u.w < mk) { mk = u.w; mi = base + 3; }
            }
        }
    }

    int rank[16];
    #pragma unroll
    for (int e = 0; e < 16; ++e) {
        int r = 0;
        #pragma unroll
        for (int f = 0; f < 16; ++f) r += (ixs[f] < ixs[e]) ? 1 : 0;
        rank[e] = r;
    }

    uint32_t mask = 0;
    #pragma unroll
    for (int e = 0; e < 16; ++e) {
        const int ix = ixs[e];
        const int lane_t = (ix >> 2) & 63;
        const int bitpos = ((ix >> 8) << 2) | (ix & 3);
        if (lane == lane_t) mask |= (1u << bitpos);
    }
    #pragma unroll
    for (int j = 0; j < 8; ++j) {
        float4 v;
        v.x = (mask >> (j * 4 + 0)) & 1u ? 1.f : 0.f;
        v.y = (mask >> (j * 4 + 1)) & 1u ? 1.f : 0.f;
        v.z = (mask >> (j * 4 + 2)) & 1u ? 1.f : 0.f;
        v.w = (mask >> (j * 4 + 3)) & 1u ? 1.f : 0.f;
        *(float4*)(srowp + j * 256 + lane * 4) = v;
    }

    const float* srow = S + (size_t)g * F;
    const float* rb = Rv + (size_t)bz * N * F;
    float4 vs = {0.f, 0.f, 0.f, 0.f};
    if (lane < 32) vs = *(const float4*)(srow + lane * 4);
    #pragma unroll
    for (int e = 0; e < 16; ++e) {
        float4 v = vs;
        if (lane >= 32)
            v = *(const float4*)(rb + (size_t)ixs[e] * F + (lane - 32) * 4);
        *(float4*)(edges_out + ((size_t)g * K_NE + rank[e]) * 256 + lane * 4) = v;
    }
}

extern "C" void kernel_launch(void* const* d_in, const int* in_sizes, int n_in,
                              void* d_out, int out_size, void* d_ws, size_t ws_size,
                              hipStream_t stream) {
    (void)in_sizes; (void)n_in; (void)out_size; (void)ws_size;
    const float* recv = (const float*)d_in[0];
    const float* send = (const float*)d_in[1];
    float* out = (float*)d_out;
    float* sender_mat = out + EDGE_FLOATS;       // score scratch, then conn matrix
    float* x2 = (float*)((char*)d_ws + (262144u * 4));
    float* y2 = x2 + NSEND;

    // f16 hi/lo staging lives in the edges region (dead until topk_fused).
    _Float16* SH = (_Float16*)out;
    _Float16* SL = SH + NSEND * F;
    _Float16* RH = SL + NSEND * F;
    _Float16* RL = RH + NSEND * F;               // total 16.8 MB << 256 MB

    norms_kernel<<<4096, 256, 0, stream>>>(send, x2);
    norms_kernel<<<4096, 256, 0, stream>>>(recv, y2);
    convert_kernel<<<4096, 256, 0, stream>>>(send, recv, SH, SL, RH, RL);
    dim3 g1(16, 16, 8);
    score_mfma_kernel<<<g1, 256, 0, stream>>>(SH, SL, RH, RL, x2, y2, sender_mat);
    topk_fused_kernel<<<4096, 256, 0, stream>>>(send, recv, sender_mat, out);
}